// Round 13
// baseline (167.760 us; speedup 1.0000x reference)
//
#include <hip/hip_runtime.h>

// 3-layer GCN on MI355X:  out = S^3(x · (W0 W1 W2)),  S = scatter-add over E edges.
// N = 100000, E = 1200000, D = 64.
//
// Per launch (6 dispatches, no cross-call state):
//   k_wchain  : Wc = W0 @ W1 @ W2; zero csr0           (1 block)
//   k_gemmcvt : B0 = bf16(x @ Wc), register-blocked 4x4, unroll-8;
//               first 64 blocks write LOCAL segment hists to hs[64][512]
//               (dense stores -- R10-R12's 262K hot-line global atomics removed)
//   k_apart   : reduce hs columns + local scan + LDS counting-sort 4096-edge
//               blocks -> packed (src<<8|lr) per-segment runs (cursor = padded csr0)
//   k_bplace  : reduce hs + local scan + per-segment LDS counting sort -> rp + cs
//   k_aggc2   : agg layer 1 (8 lanes x 16 B, 8 rows/wave)
//   k_aggc    : agg layer 2 (16 lanes x 8 B, 4 rows/wave)
//   k_aggw    : agg layer 3, f32 output

#define GCN_D 64
#define SEGSHIFT 8
#define SEGROWS 256          // dst rows per segment
#define MAXSEG 512           // compile-time LDS capacity (N <= 131072)
#define A_EPB 4096           // edges per k_apart block
#define NHB 64               // gemmcvt blocks that histogram
#define CP 16                // csr0 padding (ints) -> one 64B line per counter

typedef unsigned short ushort;

__device__ __forceinline__ float bf2f(ushort u) {
    union { unsigned u; float f; } c; c.u = ((unsigned)u) << 16; return c.f;
}
__device__ __forceinline__ float bflo(unsigned u) {
    union { unsigned u; float f; } c; c.u = u << 16; return c.f;
}
__device__ __forceinline__ float bfhi(unsigned u) {
    union { unsigned u; float f; } c; c.u = u & 0xFFFF0000u; return c.f;
}
// RNE f32 -> bf16 (finite inputs): add 0x7FFF + lsb(bit16), truncate.
__device__ __forceinline__ ushort f2bf(float f) {
    union { float f; unsigned u; } c; c.f = f;
    const unsigned r = 0x7FFFu + ((c.u >> 16) & 1u);
    return (ushort)((c.u + r) >> 16);
}
__device__ __forceinline__ unsigned pack2(float a, float b) {
    return (unsigned)f2bf(a) | ((unsigned)f2bf(b) << 16);
}

// ---------------- Wc = W0 @ W1 @ W2 (single block); zero csr0 ----------------
__global__ __launch_bounds__(256) void k_wchain(const float* __restrict__ W0,
                                                const float* __restrict__ W1,
                                                const float* __restrict__ W2,
                                                float* __restrict__ Wc,
                                                int* __restrict__ csr0) {
    __shared__ float A[4096], B[4096], T[4096];
    const int t = threadIdx.x;
    for (int i = t; i < MAXSEG * CP; i += 256) csr0[i] = 0;
    for (int i = t; i < 1024; i += 256) {
        ((float4*)A)[i] = ((const float4*)W0)[i];
        ((float4*)B)[i] = ((const float4*)W1)[i];
    }
    __syncthreads();
#pragma unroll
    for (int g = 0; g < 4; ++g) {
        const int idx = t + 256 * g;
        const int r = idx >> 4, c4 = idx & 15;
        float4 acc = make_float4(0.f, 0.f, 0.f, 0.f);
#pragma unroll
        for (int k = 0; k < 64; ++k) {
            const float a = A[r * 64 + k];
            const float4 b = ((float4*)B)[k * 16 + c4];
            acc.x = fmaf(a, b.x, acc.x); acc.y = fmaf(a, b.y, acc.y);
            acc.z = fmaf(a, b.z, acc.z); acc.w = fmaf(a, b.w, acc.w);
        }
        ((float4*)T)[idx] = acc;
    }
    __syncthreads();
    for (int i = t; i < 1024; i += 256) ((float4*)B)[i] = ((const float4*)W2)[i];
    __syncthreads();
#pragma unroll
    for (int g = 0; g < 4; ++g) {
        const int idx = t + 256 * g;
        const int r = idx >> 4, c4 = idx & 15;
        float4 acc = make_float4(0.f, 0.f, 0.f, 0.f);
#pragma unroll
        for (int k = 0; k < 64; ++k) {
            const float a = T[r * 64 + k];
            const float4 b = ((float4*)B)[k * 16 + c4];
            acc.x = fmaf(a, b.x, acc.x); acc.y = fmaf(a, b.y, acc.y);
            acc.z = fmaf(a, b.z, acc.z); acc.w = fmaf(a, b.w, acc.w);
        }
        ((float4*)Wc)[idx] = acc;
    }
}

// ---------------- GEMM + convert (+ local segment hists, no global atomics) --
__global__ __launch_bounds__(256, 3) void k_gemmcvt(const float* __restrict__ X,
                                                    const float* __restrict__ Wc,
                                                    ushort* __restrict__ B,
                                                    const int* __restrict__ ei,
                                                    int* __restrict__ hs,
                                                    int nrows, int E) {
    __shared__ float Wl[4096];
    __shared__ float Xl[64][68];
    __shared__ int h[MAXSEG];
    const int tid = threadIdx.x;
    for (int i = tid; i < 1024; i += 256) ((float4*)Wl)[i] = ((const float4*)Wc)[i];

    const int rowBase = blockIdx.x * 64;
    for (int i = tid; i < 1024; i += 256) {
        const int r = i >> 4, c4 = i & 15;
        const int gr = rowBase + r;
        const float4 v = (gr < nrows) ? ((const float4*)X)[(size_t)gr * 16 + c4]
                                      : make_float4(0.f, 0.f, 0.f, 0.f);
        *(float4*)&Xl[r][c4 * 4] = v;
    }
    __syncthreads();

    const int tr = tid >> 4;
    const int tc = tid & 15;
    float4 a0 = make_float4(0.f, 0.f, 0.f, 0.f);
    float4 a1 = a0, a2 = a0, a3 = a0;
#pragma unroll 8
    for (int k = 0; k < 64; ++k) {
        const float4 w4 = ((const float4*)Wl)[k * 16 + tc];
        const float x0 = Xl[tr][k];
        const float x1 = Xl[tr + 16][k];
        const float x2 = Xl[tr + 32][k];
        const float x3 = Xl[tr + 48][k];
        a0.x = fmaf(x0, w4.x, a0.x); a0.y = fmaf(x0, w4.y, a0.y);
        a0.z = fmaf(x0, w4.z, a0.z); a0.w = fmaf(x0, w4.w, a0.w);
        a1.x = fmaf(x1, w4.x, a1.x); a1.y = fmaf(x1, w4.y, a1.y);
        a1.z = fmaf(x1, w4.z, a1.z); a1.w = fmaf(x1, w4.w, a1.w);
        a2.x = fmaf(x2, w4.x, a2.x); a2.y = fmaf(x2, w4.y, a2.y);
        a2.z = fmaf(x2, w4.z, a2.z); a2.w = fmaf(x2, w4.w, a2.w);
        a3.x = fmaf(x3, w4.x, a3.x); a3.y = fmaf(x3, w4.y, a3.y);
        a3.z = fmaf(x3, w4.z, a3.z); a3.w = fmaf(x3, w4.w, a3.w);
    }
    {
        const int r0 = rowBase + tr;
        ushort4 o;
        if (r0 < nrows) {
            o.x = f2bf(a0.x); o.y = f2bf(a0.y); o.z = f2bf(a0.z); o.w = f2bf(a0.w);
            ((ushort4*)B)[(size_t)r0 * 16 + tc] = o;
        }
        if (r0 + 16 < nrows) {
            o.x = f2bf(a1.x); o.y = f2bf(a1.y); o.z = f2bf(a1.z); o.w = f2bf(a1.w);
            ((ushort4*)B)[(size_t)(r0 + 16) * 16 + tc] = o;
        }
        if (r0 + 32 < nrows) {
            o.x = f2bf(a2.x); o.y = f2bf(a2.y); o.z = f2bf(a2.z); o.w = f2bf(a2.w);
            ((ushort4*)B)[(size_t)(r0 + 32) * 16 + tc] = o;
        }
        if (r0 + 48 < nrows) {
            o.x = f2bf(a3.x); o.y = f2bf(a3.y); o.z = f2bf(a3.z); o.w = f2bf(a3.w);
            ((ushort4*)B)[(size_t)(r0 + 48) * 16 + tc] = o;
        }
    }

    // local segment hist (first NHB blocks); DENSE store, no global atomics
    if (blockIdx.x < NHB) {
        for (int i = tid; i < MAXSEG; i += 256) h[i] = 0;
        __syncthreads();
        for (int e = blockIdx.x * 256 + tid; e < E; e += NHB * 256)
            atomicAdd(&h[ei[E + e] >> SEGSHIFT], 1);
        __syncthreads();
        for (int i = tid; i < MAXSEG; i += 256)
            hs[blockIdx.x * MAXSEG + i] = h[i];
    }
}

// ---------------- A-partition: hs-reduce + local scan + LDS counting sort ----
// Packed word: (src << 8) | (dst & 255). src < 2^24 required.
__global__ __launch_bounds__(512) void k_apart(const int* __restrict__ ei,
                                               const int* __restrict__ hs,
                                               int* __restrict__ csr0,
                                               unsigned* __restrict__ ebuf, int E) {
    __shared__ int hist[MAXSEG], lofs[MAXSEG], cur[MAXSEG], gbase[MAXSEG], goffx[MAXSEG];
    __shared__ unsigned stg[A_EPB];
    __shared__ ushort stg2[A_EPB];
    const int t = threadIdx.x;
    const int base = blockIdx.x * A_EPB;
    const int cnt = min(A_EPB, E - base);

    // global per-segment counts: reduce hs columns (L2-hot 128 KB)
    int gv = 0;
    for (int b = 0; b < NHB; ++b) gv += hs[b * MAXSEG + t];
    goffx[t] = gv; __syncthreads();
    for (int off = 1; off < MAXSEG; off <<= 1) {
        const int y = (t >= off) ? goffx[t - off] : 0;
        __syncthreads();
        goffx[t] += y;
        __syncthreads();
    }
    const int gexcl = goffx[t] - gv;
    goffx[t] = gexcl;
    hist[t] = 0;
    __syncthreads();

    unsigned my[8]; int mb[8];
#pragma unroll
    for (int j = 0; j < 8; ++j) {
        const int i = t + j * 512;
        if (i < cnt) {
            const int e = base + i;
            const unsigned s = (unsigned)ei[e];
            const unsigned d = (unsigned)ei[E + e];
            my[j] = (s << 8) | (d & (SEGROWS - 1));
            mb[j] = (int)(d >> SEGSHIFT);
            atomicAdd(&hist[mb[j]], 1);
        } else mb[j] = -1;
    }
    __syncthreads();

    // exclusive block scan of hist -> lofs (and cursor copy)
    {
        const int v = hist[t];
        lofs[t] = v; __syncthreads();
        for (int off = 1; off < MAXSEG; off <<= 1) {
            const int y = (t >= off) ? lofs[t - off] : 0;
            __syncthreads();
            lofs[t] += y;
            __syncthreads();
        }
        const int excl = lofs[t] - v;
        __syncthreads();
        lofs[t] = excl; cur[t] = excl;
    }
    __syncthreads();

    // place packed words into stg grouped by segment; remember segment id
#pragma unroll
    for (int j = 0; j < 8; ++j) {
        if (mb[j] >= 0) {
            const int p = atomicAdd(&cur[mb[j]], 1);
            stg[p] = my[j];
            stg2[p] = (ushort)mb[j];
        }
    }
    __syncthreads();

    // reserve global space per segment (padded counters: 1 line each)
    {
        const int c = hist[t];
        const int p = c ? atomicAdd(&csr0[t * CP], c) : 0;
        gbase[t] = goffx[t] + p;
    }
    __syncthreads();

    // copy runs out (consecutive i within a run -> coalesced global writes)
    for (int i = t; i < cnt; i += 512) {
        const int b = (int)stg2[i];
        ebuf[(size_t)gbase[b] + (unsigned)(i - lofs[b])] = stg[i];
    }
}

// ---------------- B-place: hs-reduce + local scan + per-segment sort ---------
__global__ __launch_bounds__(SEGROWS) void k_bplace(const unsigned* __restrict__ ebuf,
                                                    const int* __restrict__ hs,
                                                    int* __restrict__ rp,
                                                    int* __restrict__ cs, int N, int E) {
    __shared__ int h[SEGROWS], ofs[SEGROWS], gpart[SEGROWS];
    __shared__ int gx[MAXSEG], gcnt[MAXSEG];
    const int s = blockIdx.x;
    const int t = threadIdx.x;

    // reduce hs columns (2 segments per thread) then scan -> gx
    int a0 = 0, a1 = 0;
    for (int b = 0; b < NHB; ++b) {
        a0 += hs[b * MAXSEG + 2 * t];
        a1 += hs[b * MAXSEG + 2 * t + 1];
    }
    gcnt[2 * t] = a0; gcnt[2 * t + 1] = a1;
    const int ps = a0 + a1;
    gpart[t] = ps; __syncthreads();
    for (int off = 1; off < SEGROWS; off <<= 1) {
        const int y = (t >= off) ? gpart[t - off] : 0;
        __syncthreads();
        gpart[t] += y;
        __syncthreads();
    }
    const int ex = gpart[t] - ps;
    gx[2 * t] = ex;
    gx[2 * t + 1] = ex + a0;
    if (s == 0 && t == 0) rp[N] = E;
    __syncthreads();

    const int e0 = gx[s];
    const int e1 = e0 + gcnt[s];

    h[t] = 0; __syncthreads();
    for (int e = e0 + t; e < e1; e += SEGROWS)
        atomicAdd(&h[ebuf[e] & (SEGROWS - 1)], 1);
    __syncthreads();

    const int v = h[t];
    ofs[t] = v; __syncthreads();
    for (int off = 1; off < SEGROWS; off <<= 1) {
        const int y = (t >= off) ? ofs[t - off] : 0;
        __syncthreads();
        ofs[t] += y;
        __syncthreads();
    }
    const int excl = ofs[t] - v;
    const int r = s * SEGROWS + t;
    if (r < N) rp[r] = e0 + excl;
    __syncthreads();
    ofs[t] = excl;                 // becomes the within-segment cursor
    __syncthreads();

    for (int e = e0 + t; e < e1; e += SEGROWS) {
        const unsigned pr = ebuf[e];
        const int lr = (int)(pr & (SEGROWS - 1));
        const int p = atomicAdd(&ofs[lr], 1);
        cs[e0 + p] = (int)(pr >> 8);
    }
}

// ---------------- Agg variant A: 8 lanes x 16 B, 8 rows/wave -----------------
__global__ __launch_bounds__(256) void k_aggc2(const ushort* __restrict__ B,
                                               const int* __restrict__ rp,
                                               const int* __restrict__ cs,
                                               ushort* __restrict__ out, int N) {
    const int t = threadIdx.x;
    const int gw = (blockIdx.x * 256 + t) >> 6;
    const int lane = t & 63;
    const int f8 = lane & 7;
    const int r = gw * 8 + (lane >> 3);
    if (r >= N) return;

    const int e0 = rp[r];
    const int e1 = rp[r + 1];
    const uint4* Bv = (const uint4*)B;

    float acc[8] = {0.f, 0.f, 0.f, 0.f, 0.f, 0.f, 0.f, 0.f};
    int e = e0;
    for (; e + 7 < e1; e += 8) {
        uint4 u[8];
#pragma unroll
        for (int j = 0; j < 8; ++j) u[j] = Bv[(size_t)cs[e + j] * 8 + f8];
#pragma unroll
        for (int j = 0; j < 8; ++j) {
            acc[0] += bflo(u[j].x); acc[1] += bfhi(u[j].x);
            acc[2] += bflo(u[j].y); acc[3] += bfhi(u[j].y);
            acc[4] += bflo(u[j].z); acc[5] += bfhi(u[j].z);
            acc[6] += bflo(u[j].w); acc[7] += bfhi(u[j].w);
        }
    }
    for (; e < e1; ++e) {
        const uint4 u = Bv[(size_t)cs[e] * 8 + f8];
        acc[0] += bflo(u.x); acc[1] += bfhi(u.x);
        acc[2] += bflo(u.y); acc[3] += bfhi(u.y);
        acc[4] += bflo(u.z); acc[5] += bfhi(u.z);
        acc[6] += bflo(u.w); acc[7] += bfhi(u.w);
    }
    uint4 o;
    o.x = pack2(acc[0], acc[1]); o.y = pack2(acc[2], acc[3]);
    o.z = pack2(acc[4], acc[5]); o.w = pack2(acc[6], acc[7]);
    ((uint4*)out)[(size_t)r * 8 + f8] = o;
}

// ---------------- Agg variant B: 16 lanes x 8 B, 4 rows/wave -----------------
__global__ __launch_bounds__(256) void k_aggc(const ushort* __restrict__ B,
                                              const int* __restrict__ rp,
                                              const int* __restrict__ cs,
                                              ushort* __restrict__ out, int N) {
    const int t = threadIdx.x;
    const int gw = (blockIdx.x * 256 + t) >> 6;
    const int lane = t & 63;
    const int f4 = lane & 15;
    const int r = gw * 4 + (lane >> 4);
    if (r >= N) return;

    const int e0 = rp[r];
    const int e1 = rp[r + 1];
    const ushort4* Bv = (const ushort4*)B;

    float4 acc = make_float4(0.f, 0.f, 0.f, 0.f);
    int e = e0;
    for (; e + 7 < e1; e += 8) {
        ushort4 u[8];
#pragma unroll
        for (int j = 0; j < 8; ++j) u[j] = Bv[(size_t)cs[e + j] * 16 + f4];
#pragma unroll
        for (int j = 0; j < 8; ++j) {
            acc.x += bf2f(u[j].x); acc.y += bf2f(u[j].y);
            acc.z += bf2f(u[j].z); acc.w += bf2f(u[j].w);
        }
    }
    for (; e + 3 < e1; e += 4) {
        ushort4 u[4];
#pragma unroll
        for (int j = 0; j < 4; ++j) u[j] = Bv[(size_t)cs[e + j] * 16 + f4];
#pragma unroll
        for (int j = 0; j < 4; ++j) {
            acc.x += bf2f(u[j].x); acc.y += bf2f(u[j].y);
            acc.z += bf2f(u[j].z); acc.w += bf2f(u[j].w);
        }
    }
    for (; e < e1; ++e) {
        const ushort4 u = Bv[(size_t)cs[e] * 16 + f4];
        acc.x += bf2f(u.x); acc.y += bf2f(u.y);
        acc.z += bf2f(u.z); acc.w += bf2f(u.w);
    }
    ushort4 o;
    o.x = f2bf(acc.x); o.y = f2bf(acc.y); o.z = f2bf(acc.z); o.w = f2bf(acc.w);
    ((ushort4*)out)[(size_t)r * 16 + f4] = o;
}

// ---------------- Final aggregation: f32 output ------------------------------
__global__ __launch_bounds__(256) void k_aggw(const ushort* __restrict__ B,
                                              const int* __restrict__ rp,
                                              const int* __restrict__ cs,
                                              float* __restrict__ out, int N) {
    const int t = threadIdx.x;
    const int gw = (blockIdx.x * 256 + t) >> 6;
    const int lane = t & 63;
    const int f4 = lane & 15;
    const int r = gw * 4 + (lane >> 4);
    if (r >= N) return;

    const int e0 = rp[r];
    const int e1 = rp[r + 1];
    const ushort4* Bv = (const ushort4*)B;

    float4 acc = make_float4(0.f, 0.f, 0.f, 0.f);
    int e = e0;
    for (; e + 7 < e1; e += 8) {
        ushort4 u[8];
#pragma unroll
        for (int j = 0; j < 8; ++j) u[j] = Bv[(size_t)cs[e + j] * 16 + f4];
#pragma unroll
        for (int j = 0; j < 8; ++j) {
            acc.x += bf2f(u[j].x); acc.y += bf2f(u[j].y);
            acc.z += bf2f(u[j].z); acc.w += bf2f(u[j].w);
        }
    }
    for (; e + 3 < e1; e += 4) {
        ushort4 u[4];
#pragma unroll
        for (int j = 0; j < 4; ++j) u[j] = Bv[(size_t)cs[e + j] * 16 + f4];
#pragma unroll
        for (int j = 0; j < 4; ++j) {
            acc.x += bf2f(u[j].x); acc.y += bf2f(u[j].y);
            acc.z += bf2f(u[j].z); acc.w += bf2f(u[j].w);
        }
    }
    for (; e < e1; ++e) {
        const ushort4 u = Bv[(size_t)cs[e] * 16 + f4];
        acc.x += bf2f(u.x); acc.y += bf2f(u.y);
        acc.z += bf2f(u.z); acc.w += bf2f(u.w);
    }
    ((float4*)out)[(size_t)r * 16 + f4] = acc;
}

// ---------------- R1 fallback kernels ----------------
__global__ __launch_bounds__(256) void gcn_gemm64(const float* __restrict__ X,
                                                  const float* __restrict__ W,
                                                  float* __restrict__ H,
                                                  int nrows) {
    __shared__ float Wl[64 * 64];
    __shared__ float Xl[16][65];
    const int tid = threadIdx.x;
    for (int i = tid; i < 1024; i += 256) ((float4*)Wl)[i] = ((const float4*)W)[i];
    const int rowBase = blockIdx.x * 16;
    const int lr = tid >> 4;
    const int lc = tid & 15;
    const int grow = rowBase + lr;
    if (grow < nrows) {
        float4 xv = ((const float4*)X)[(long long)grow * 16 + lc];
        Xl[lr][lc * 4 + 0] = xv.x; Xl[lr][lc * 4 + 1] = xv.y;
        Xl[lr][lc * 4 + 2] = xv.z; Xl[lr][lc * 4 + 3] = xv.w;
    }
    __syncthreads();
    float4 acc = make_float4(0.f, 0.f, 0.f, 0.f);
#pragma unroll
    for (int k = 0; k < 64; ++k) {
        const float xv = Xl[lr][k];
        const float4 w4 = ((float4*)Wl)[k * 16 + lc];
        acc.x = fmaf(xv, w4.x, acc.x); acc.y = fmaf(xv, w4.y, acc.y);
        acc.z = fmaf(xv, w4.z, acc.z); acc.w = fmaf(xv, w4.w, acc.w);
    }
    if (grow < nrows) ((float4*)H)[(long long)grow * 16 + lc] = acc;
}

__global__ __launch_bounds__(256) void gcn_scatter(const float* __restrict__ H,
                                                   const int* __restrict__ ei,
                                                   float* __restrict__ out,
                                                   int nedges) {
    const long long t = (long long)blockIdx.x * 256 + threadIdx.x;
    const int e = (int)(t >> 4);
    if (e >= nedges) return;
    const int lc = (int)(t & 15);
    const int s = ei[e];
    const int d = ei[nedges + e];
    const float4 v = ((const float4*)H)[(long long)s * 16 + lc];
    float* o = out + (long long)d * GCN_D + lc * 4;
    atomicAdd(o + 0, v.x);
    atomicAdd(o + 1, v.y);
    atomicAdd(o + 2, v.z);
    atomicAdd(o + 3, v.w);
}

extern "C" void kernel_launch(void* const* d_in, const int* in_sizes, int n_in,
                              void* d_out, int out_size, void* d_ws, size_t ws_size,
                              hipStream_t stream) {
    const float* x  = (const float*)d_in[0];
    const int*   ei = (const int*)d_in[1];   // [2,E] flat: src then dst (int32)
    const float* W0 = (const float*)d_in[2];
    const float* W1 = (const float*)d_in[3];
    const float* W2 = (const float*)d_in[4];
    float* out = (float*)d_out;

    const int N_ = in_sizes[0] / GCN_D;
    const int E_ = in_sizes[1] / 2;
    const int NSEG = (N_ + SEGROWS - 1) >> SEGSHIFT;

    // ws layout:
    //   B0 (N*64 bf16) | REG (max(N*64 bf16, E*4) -- B1/ebuf alias, disjoint
    //   lifetimes) | rp (N+2) | hs (NHB*512) | csr0 (512*CP) | Wc (4096 f32) | cs (E)
    uintptr_t base = (uintptr_t)d_ws;
    ushort* B0 = (ushort*)base;
    const size_t bfBytes  = (size_t)N_ * GCN_D * 2;
    const size_t regBytes = bfBytes > (size_t)E_ * 4 ? bfBytes : (size_t)E_ * 4;
    ushort*   B1   = (ushort*)(base + bfBytes);
    unsigned* ebuf = (unsigned*)B1;          // alias: dead before first agg
    int* rp    = (int*)(base + bfBytes + regBytes);
    int* hs    = rp + (N_ + 2);
    int* csr0  = hs + NHB * MAXSEG;
    float* Wc  = (float*)(csr0 + MAXSEG * CP);
    int* cs    = (int*)(Wc + 4096);
    const size_t needed = ((uintptr_t)(cs + E_) - base);

    const int gemmBlocks = (N_ + 63) / 64;
    const int gcBlocks = gemmBlocks > NHB ? gemmBlocks : NHB;

    if (NSEG <= MAXSEG && N_ < (1 << 24) && ws_size >= needed) {
        k_wchain<<<1, 256, 0, stream>>>(W0, W1, W2, Wc, csr0);
        k_gemmcvt<<<gcBlocks, 256, 0, stream>>>(x, Wc, B0, ei, hs, N_, E_);
        k_apart<<<(E_ + A_EPB - 1) / A_EPB, 512, 0, stream>>>(ei, hs, csr0, ebuf, E_);
        k_bplace<<<NSEG, SEGROWS, 0, stream>>>(ebuf, hs, rp, cs, N_, E_);

        const int aggBlocks  = (N_ + 15) / 16;    // 4 rows/wave
        const int aggBlocks2 = (N_ + 31) / 32;    // 8 rows/wave
        k_aggc2<<<aggBlocks2, 256, 0, stream>>>(B0, rp, cs, B1, N_);  // a1 (16B/lane)
        k_aggc <<<aggBlocks,  256, 0, stream>>>(B1, rp, cs, B0, N_);  // a2 (8B/lane)
        k_aggw <<<aggBlocks,  256, 0, stream>>>(B0, rp, cs, out, N_); // a3 -> f32
    } else {
        // Fallback: R1 path (needs only h = N*64 f32).
        float* h = (float*)d_ws;
        const int scatBlocks = (int)(((long long)E_ * 16 + 255) / 256);
        const int gb16 = (N_ + 15) / 16;
        const float* curAct = x;
        for (int l = 0; l < 3; ++l) {
            const float* Wl = (l == 0) ? W0 : (l == 1) ? W1 : W2;
            gcn_gemm64<<<gb16, 256, 0, stream>>>(curAct, Wl, h, N_);
            hipMemsetAsync(out, 0, (size_t)N_ * GCN_D * sizeof(float), stream);
            gcn_scatter<<<scatBlocks, 256, 0, stream>>>(h, ei, out, E_);
            curAct = out;
        }
    }
}

// Round 14
// 159.174 us; speedup vs baseline: 1.0539x; 1.0539x over previous
//
#include <hip/hip_runtime.h>

// 3-layer GCN on MI355X:  out = S^3(x · (W0 W1 W2)),  S = scatter-add over E edges.
// N = 100000, E = 1200000, D = 64.
//
// Per launch (7 dispatches, no cross-call state):
//   k_wchain  : Wc = W0 @ W1 @ W2; zero ghistP + csr0  (1 block)
//   k_gemmcvt : B0 = bf16(x @ Wc), register-blocked 4x4, unroll-8;
//               first 512 blocks histogram dst segments with STATIC 10-deep
//               unrolled loads (MLP) + PADDED global accumulation (1 line/bin)
//   k_apart   : local scan of ghistP + LDS counting-sort 4096-edge blocks ->
//               packed (src<<8|lr) per-segment runs (cursor = padded csr0)
//   k_bplace  : local scan + per-segment LDS counting sort -> rp + cs
//   k_aggc2   : agg layer 1 (8 lanes x 16 B, 8 rows/wave)
//   k_aggc    : agg layer 2 (16 lanes x 8 B, 4 rows/wave)
//   k_aggw    : agg layer 3, f32 output

#define GCN_D 64
#define SEGSHIFT 8
#define SEGROWS 256          // dst rows per segment
#define MAXSEG 512           // compile-time LDS capacity (N <= 131072)
#define A_EPB 4096           // edges per k_apart block
#define HISTB 512            // gemmcvt blocks that histogram
#define HITER 10             // static unroll depth: covers E <= 1,310,720
#define CP 16                // padding (ints) -> one 64B line per counter

typedef unsigned short ushort;

__device__ __forceinline__ float bf2f(ushort u) {
    union { unsigned u; float f; } c; c.u = ((unsigned)u) << 16; return c.f;
}
__device__ __forceinline__ float bflo(unsigned u) {
    union { unsigned u; float f; } c; c.u = u << 16; return c.f;
}
__device__ __forceinline__ float bfhi(unsigned u) {
    union { unsigned u; float f; } c; c.u = u & 0xFFFF0000u; return c.f;
}
// RNE f32 -> bf16 (finite inputs): add 0x7FFF + lsb(bit16), truncate.
__device__ __forceinline__ ushort f2bf(float f) {
    union { float f; unsigned u; } c; c.f = f;
    const unsigned r = 0x7FFFu + ((c.u >> 16) & 1u);
    return (ushort)((c.u + r) >> 16);
}
__device__ __forceinline__ unsigned pack2(float a, float b) {
    return (unsigned)f2bf(a) | ((unsigned)f2bf(b) << 16);
}

// ---------------- Wc = W0 @ W1 @ W2 (single block); zero ghistP/csr0 ---------
__global__ __launch_bounds__(256) void k_wchain(const float* __restrict__ W0,
                                                const float* __restrict__ W1,
                                                const float* __restrict__ W2,
                                                float* __restrict__ Wc,
                                                int* __restrict__ ghistP,
                                                int* __restrict__ csr0) {
    __shared__ float A[4096], B[4096], T[4096];
    const int t = threadIdx.x;
    for (int i = t; i < MAXSEG * CP; i += 256) { ghistP[i] = 0; csr0[i] = 0; }
    for (int i = t; i < 1024; i += 256) {
        ((float4*)A)[i] = ((const float4*)W0)[i];
        ((float4*)B)[i] = ((const float4*)W1)[i];
    }
    __syncthreads();
#pragma unroll
    for (int g = 0; g < 4; ++g) {
        const int idx = t + 256 * g;
        const int r = idx >> 4, c4 = idx & 15;
        float4 acc = make_float4(0.f, 0.f, 0.f, 0.f);
#pragma unroll
        for (int k = 0; k < 64; ++k) {
            const float a = A[r * 64 + k];
            const float4 b = ((float4*)B)[k * 16 + c4];
            acc.x = fmaf(a, b.x, acc.x); acc.y = fmaf(a, b.y, acc.y);
            acc.z = fmaf(a, b.z, acc.z); acc.w = fmaf(a, b.w, acc.w);
        }
        ((float4*)T)[idx] = acc;
    }
    __syncthreads();
    for (int i = t; i < 1024; i += 256) ((float4*)B)[i] = ((const float4*)W2)[i];
    __syncthreads();
#pragma unroll
    for (int g = 0; g < 4; ++g) {
        const int idx = t + 256 * g;
        const int r = idx >> 4, c4 = idx & 15;
        float4 acc = make_float4(0.f, 0.f, 0.f, 0.f);
#pragma unroll
        for (int k = 0; k < 64; ++k) {
            const float a = T[r * 64 + k];
            const float4 b = ((float4*)B)[k * 16 + c4];
            acc.x = fmaf(a, b.x, acc.x); acc.y = fmaf(a, b.y, acc.y);
            acc.z = fmaf(a, b.z, acc.z); acc.w = fmaf(a, b.w, acc.w);
        }
        ((float4*)Wc)[idx] = acc;
    }
}

// ---------------- GEMM + convert (+ fused hist: MLP loads, padded atomics) ---
__global__ __launch_bounds__(256, 3) void k_gemmcvt(const float* __restrict__ X,
                                                    const float* __restrict__ Wc,
                                                    ushort* __restrict__ B,
                                                    const int* __restrict__ ei,
                                                    int* __restrict__ ghistP,
                                                    int nrows, int E) {
    __shared__ float Wl[4096];
    __shared__ float Xl[64][68];
    __shared__ int h[MAXSEG];
    const int tid = threadIdx.x;
    for (int i = tid; i < 1024; i += 256) ((float4*)Wl)[i] = ((const float4*)Wc)[i];

    const int rowBase = blockIdx.x * 64;
    for (int i = tid; i < 1024; i += 256) {
        const int r = i >> 4, c4 = i & 15;
        const int gr = rowBase + r;
        const float4 v = (gr < nrows) ? ((const float4*)X)[(size_t)gr * 16 + c4]
                                      : make_float4(0.f, 0.f, 0.f, 0.f);
        *(float4*)&Xl[r][c4 * 4] = v;
    }
    __syncthreads();

    const int tr = tid >> 4;
    const int tc = tid & 15;
    float4 a0 = make_float4(0.f, 0.f, 0.f, 0.f);
    float4 a1 = a0, a2 = a0, a3 = a0;
#pragma unroll 8
    for (int k = 0; k < 64; ++k) {
        const float4 w4 = ((const float4*)Wl)[k * 16 + tc];
        const float x0 = Xl[tr][k];
        const float x1 = Xl[tr + 16][k];
        const float x2 = Xl[tr + 32][k];
        const float x3 = Xl[tr + 48][k];
        a0.x = fmaf(x0, w4.x, a0.x); a0.y = fmaf(x0, w4.y, a0.y);
        a0.z = fmaf(x0, w4.z, a0.z); a0.w = fmaf(x0, w4.w, a0.w);
        a1.x = fmaf(x1, w4.x, a1.x); a1.y = fmaf(x1, w4.y, a1.y);
        a1.z = fmaf(x1, w4.z, a1.z); a1.w = fmaf(x1, w4.w, a1.w);
        a2.x = fmaf(x2, w4.x, a2.x); a2.y = fmaf(x2, w4.y, a2.y);
        a2.z = fmaf(x2, w4.z, a2.z); a2.w = fmaf(x2, w4.w, a2.w);
        a3.x = fmaf(x3, w4.x, a3.x); a3.y = fmaf(x3, w4.y, a3.y);
        a3.z = fmaf(x3, w4.z, a3.z); a3.w = fmaf(x3, w4.w, a3.w);
    }
    {
        const int r0 = rowBase + tr;
        ushort4 o;
        if (r0 < nrows) {
            o.x = f2bf(a0.x); o.y = f2bf(a0.y); o.z = f2bf(a0.z); o.w = f2bf(a0.w);
            ((ushort4*)B)[(size_t)r0 * 16 + tc] = o;
        }
        if (r0 + 16 < nrows) {
            o.x = f2bf(a1.x); o.y = f2bf(a1.y); o.z = f2bf(a1.z); o.w = f2bf(a1.w);
            ((ushort4*)B)[(size_t)(r0 + 16) * 16 + tc] = o;
        }
        if (r0 + 32 < nrows) {
            o.x = f2bf(a2.x); o.y = f2bf(a2.y); o.z = f2bf(a2.z); o.w = f2bf(a2.w);
            ((ushort4*)B)[(size_t)(r0 + 32) * 16 + tc] = o;
        }
        if (r0 + 48 < nrows) {
            o.x = f2bf(a3.x); o.y = f2bf(a3.y); o.z = f2bf(a3.z); o.w = f2bf(a3.w);
            ((ushort4*)B)[(size_t)(r0 + 48) * 16 + tc] = o;
        }
    }

    // fused segment histogram: STATIC unrolled loads (10 in flight), then LDS
    // atomics, then PADDED global accumulate (one 64B line per bin).
    if (blockIdx.x < HISTB) {
        for (int i = tid; i < MAXSEG; i += 256) h[i] = 0;
        __syncthreads();
        const int stride = HISTB * 256;
        const int e0 = blockIdx.x * 256 + tid;
        int myd[HITER];
#pragma unroll
        for (int j = 0; j < HITER; ++j) {
            const int e = e0 + j * stride;
            myd[j] = (e < E) ? ei[E + e] : -1;
        }
#pragma unroll
        for (int j = 0; j < HITER; ++j)
            if (myd[j] >= 0) atomicAdd(&h[myd[j] >> SEGSHIFT], 1);
        for (int e = e0 + HITER * stride; e < E; e += stride)   // generality tail
            atomicAdd(&h[ei[E + e] >> SEGSHIFT], 1);
        __syncthreads();
        for (int i = tid; i < MAXSEG; i += 256) {
            const int c = h[i];
            if (c) atomicAdd(&ghistP[i * CP], c);
        }
    }
}

// ---------------- A-partition: local scan + LDS counting sort ----------------
// Packed word: (src << 8) | (dst & 255). src < 2^24 required.
__global__ __launch_bounds__(512) void k_apart(const int* __restrict__ ei,
                                               const int* __restrict__ ghistP,
                                               int* __restrict__ csr0,
                                               unsigned* __restrict__ ebuf, int E) {
    __shared__ int hist[MAXSEG], lofs[MAXSEG], cur[MAXSEG], gbase[MAXSEG], goffx[MAXSEG];
    __shared__ unsigned stg[A_EPB];
    __shared__ ushort stg2[A_EPB];
    const int t = threadIdx.x;
    const int base = blockIdx.x * A_EPB;
    const int cnt = min(A_EPB, E - base);

    // global exclusive offsets: scan padded ghist locally
    const int gv = ghistP[t * CP];
    goffx[t] = gv; __syncthreads();
    for (int off = 1; off < MAXSEG; off <<= 1) {
        const int y = (t >= off) ? goffx[t - off] : 0;
        __syncthreads();
        goffx[t] += y;
        __syncthreads();
    }
    const int gexcl = goffx[t] - gv;
    goffx[t] = gexcl;
    hist[t] = 0;
    __syncthreads();

    unsigned my[8]; int mb[8];
#pragma unroll
    for (int j = 0; j < 8; ++j) {
        const int i = t + j * 512;
        if (i < cnt) {
            const int e = base + i;
            const unsigned s = (unsigned)ei[e];
            const unsigned d = (unsigned)ei[E + e];
            my[j] = (s << 8) | (d & (SEGROWS - 1));
            mb[j] = (int)(d >> SEGSHIFT);
            atomicAdd(&hist[mb[j]], 1);
        } else mb[j] = -1;
    }
    __syncthreads();

    // exclusive block scan of hist -> lofs (and cursor copy)
    {
        const int v = hist[t];
        lofs[t] = v; __syncthreads();
        for (int off = 1; off < MAXSEG; off <<= 1) {
            const int y = (t >= off) ? lofs[t - off] : 0;
            __syncthreads();
            lofs[t] += y;
            __syncthreads();
        }
        const int excl = lofs[t] - v;
        __syncthreads();
        lofs[t] = excl; cur[t] = excl;
    }
    __syncthreads();

    // place packed words into stg grouped by segment; remember segment id
#pragma unroll
    for (int j = 0; j < 8; ++j) {
        if (mb[j] >= 0) {
            const int p = atomicAdd(&cur[mb[j]], 1);
            stg[p] = my[j];
            stg2[p] = (ushort)mb[j];
        }
    }
    __syncthreads();

    // reserve global space per segment (padded counters: 1 line each)
    {
        const int c = hist[t];
        const int p = c ? atomicAdd(&csr0[t * CP], c) : 0;
        gbase[t] = goffx[t] + p;
    }
    __syncthreads();

    // copy runs out (consecutive i within a run -> coalesced global writes)
    for (int i = t; i < cnt; i += 512) {
        const int b = (int)stg2[i];
        ebuf[(size_t)gbase[b] + (unsigned)(i - lofs[b])] = stg[i];
    }
}

// ---------------- B-place: local scan + per-segment counting sort ------------
__global__ __launch_bounds__(SEGROWS) void k_bplace(const unsigned* __restrict__ ebuf,
                                                    const int* __restrict__ ghistP,
                                                    int* __restrict__ rp,
                                                    int* __restrict__ cs, int N, int E) {
    __shared__ int h[SEGROWS], ofs[SEGROWS], gpart[SEGROWS];
    __shared__ int gx[MAXSEG], gcnt[MAXSEG];
    const int s = blockIdx.x;
    const int t = threadIdx.x;

    // scan padded ghist (2 segments per thread) -> gx
    const int a0 = ghistP[(2 * t) * CP];
    const int a1 = ghistP[(2 * t + 1) * CP];
    gcnt[2 * t] = a0; gcnt[2 * t + 1] = a1;
    const int ps = a0 + a1;
    gpart[t] = ps; __syncthreads();
    for (int off = 1; off < SEGROWS; off <<= 1) {
        const int y = (t >= off) ? gpart[t - off] : 0;
        __syncthreads();
        gpart[t] += y;
        __syncthreads();
    }
    const int ex = gpart[t] - ps;
    gx[2 * t] = ex;
    gx[2 * t + 1] = ex + a0;
    if (s == 0 && t == 0) rp[N] = E;
    __syncthreads();

    const int e0 = gx[s];
    const int e1 = e0 + gcnt[s];

    h[t] = 0; __syncthreads();
    for (int e = e0 + t; e < e1; e += SEGROWS)
        atomicAdd(&h[ebuf[e] & (SEGROWS - 1)], 1);
    __syncthreads();

    const int v = h[t];
    ofs[t] = v; __syncthreads();
    for (int off = 1; off < SEGROWS; off <<= 1) {
        const int y = (t >= off) ? ofs[t - off] : 0;
        __syncthreads();
        ofs[t] += y;
        __syncthreads();
    }
    const int excl = ofs[t] - v;
    const int r = s * SEGROWS + t;
    if (r < N) rp[r] = e0 + excl;
    __syncthreads();
    ofs[t] = excl;                 // becomes the within-segment cursor
    __syncthreads();

    for (int e = e0 + t; e < e1; e += SEGROWS) {
        const unsigned pr = ebuf[e];
        const int lr = (int)(pr & (SEGROWS - 1));
        const int p = atomicAdd(&ofs[lr], 1);
        cs[e0 + p] = (int)(pr >> 8);
    }
}

// ---------------- Agg variant A: 8 lanes x 16 B, 8 rows/wave -----------------
__global__ __launch_bounds__(256) void k_aggc2(const ushort* __restrict__ B,
                                               const int* __restrict__ rp,
                                               const int* __restrict__ cs,
                                               ushort* __restrict__ out, int N) {
    const int t = threadIdx.x;
    const int gw = (blockIdx.x * 256 + t) >> 6;
    const int lane = t & 63;
    const int f8 = lane & 7;
    const int r = gw * 8 + (lane >> 3);
    if (r >= N) return;

    const int e0 = rp[r];
    const int e1 = rp[r + 1];
    const uint4* Bv = (const uint4*)B;

    float acc[8] = {0.f, 0.f, 0.f, 0.f, 0.f, 0.f, 0.f, 0.f};
    int e = e0;
    for (; e + 7 < e1; e += 8) {
        uint4 u[8];
#pragma unroll
        for (int j = 0; j < 8; ++j) u[j] = Bv[(size_t)cs[e + j] * 8 + f8];
#pragma unroll
        for (int j = 0; j < 8; ++j) {
            acc[0] += bflo(u[j].x); acc[1] += bfhi(u[j].x);
            acc[2] += bflo(u[j].y); acc[3] += bfhi(u[j].y);
            acc[4] += bflo(u[j].z); acc[5] += bfhi(u[j].z);
            acc[6] += bflo(u[j].w); acc[7] += bfhi(u[j].w);
        }
    }
    for (; e < e1; ++e) {
        const uint4 u = Bv[(size_t)cs[e] * 8 + f8];
        acc[0] += bflo(u.x); acc[1] += bfhi(u.x);
        acc[2] += bflo(u.y); acc[3] += bfhi(u.y);
        acc[4] += bflo(u.z); acc[5] += bfhi(u.z);
        acc[6] += bflo(u.w); acc[7] += bfhi(u.w);
    }
    uint4 o;
    o.x = pack2(acc[0], acc[1]); o.y = pack2(acc[2], acc[3]);
    o.z = pack2(acc[4], acc[5]); o.w = pack2(acc[6], acc[7]);
    ((uint4*)out)[(size_t)r * 8 + f8] = o;
}

// ---------------- Agg variant B: 16 lanes x 8 B, 4 rows/wave -----------------
__global__ __launch_bounds__(256) void k_aggc(const ushort* __restrict__ B,
                                              const int* __restrict__ rp,
                                              const int* __restrict__ cs,
                                              ushort* __restrict__ out, int N) {
    const int t = threadIdx.x;
    const int gw = (blockIdx.x * 256 + t) >> 6;
    const int lane = t & 63;
    const int f4 = lane & 15;
    const int r = gw * 4 + (lane >> 4);
    if (r >= N) return;

    const int e0 = rp[r];
    const int e1 = rp[r + 1];
    const ushort4* Bv = (const ushort4*)B;

    float4 acc = make_float4(0.f, 0.f, 0.f, 0.f);
    int e = e0;
    for (; e + 7 < e1; e += 8) {
        ushort4 u[8];
#pragma unroll
        for (int j = 0; j < 8; ++j) u[j] = Bv[(size_t)cs[e + j] * 16 + f4];
#pragma unroll
        for (int j = 0; j < 8; ++j) {
            acc.x += bf2f(u[j].x); acc.y += bf2f(u[j].y);
            acc.z += bf2f(u[j].z); acc.w += bf2f(u[j].w);
        }
    }
    for (; e + 3 < e1; e += 4) {
        ushort4 u[4];
#pragma unroll
        for (int j = 0; j < 4; ++j) u[j] = Bv[(size_t)cs[e + j] * 16 + f4];
#pragma unroll
        for (int j = 0; j < 4; ++j) {
            acc.x += bf2f(u[j].x); acc.y += bf2f(u[j].y);
            acc.z += bf2f(u[j].z); acc.w += bf2f(u[j].w);
        }
    }
    for (; e < e1; ++e) {
        const ushort4 u = Bv[(size_t)cs[e] * 16 + f4];
        acc.x += bf2f(u.x); acc.y += bf2f(u.y);
        acc.z += bf2f(u.z); acc.w += bf2f(u.w);
    }
    ushort4 o;
    o.x = f2bf(acc.x); o.y = f2bf(acc.y); o.z = f2bf(acc.z); o.w = f2bf(acc.w);
    ((ushort4*)out)[(size_t)r * 16 + f4] = o;
}

// ---------------- Final aggregation: f32 output ------------------------------
__global__ __launch_bounds__(256) void k_aggw(const ushort* __restrict__ B,
                                              const int* __restrict__ rp,
                                              const int* __restrict__ cs,
                                              float* __restrict__ out, int N) {
    const int t = threadIdx.x;
    const int gw = (blockIdx.x * 256 + t) >> 6;
    const int lane = t & 63;
    const int f4 = lane & 15;
    const int r = gw * 4 + (lane >> 4);
    if (r >= N) return;

    const int e0 = rp[r];
    const int e1 = rp[r + 1];
    const ushort4* Bv = (const ushort4*)B;

    float4 acc = make_float4(0.f, 0.f, 0.f, 0.f);
    int e = e0;
    for (; e + 7 < e1; e += 8) {
        ushort4 u[8];
#pragma unroll
        for (int j = 0; j < 8; ++j) u[j] = Bv[(size_t)cs[e + j] * 16 + f4];
#pragma unroll
        for (int j = 0; j < 8; ++j) {
            acc.x += bf2f(u[j].x); acc.y += bf2f(u[j].y);
            acc.z += bf2f(u[j].z); acc.w += bf2f(u[j].w);
        }
    }
    for (; e + 3 < e1; e += 4) {
        ushort4 u[4];
#pragma unroll
        for (int j = 0; j < 4; ++j) u[j] = Bv[(size_t)cs[e + j] * 16 + f4];
#pragma unroll
        for (int j = 0; j < 4; ++j) {
            acc.x += bf2f(u[j].x); acc.y += bf2f(u[j].y);
            acc.z += bf2f(u[j].z); acc.w += bf2f(u[j].w);
        }
    }
    for (; e < e1; ++e) {
        const ushort4 u = Bv[(size_t)cs[e] * 16 + f4];
        acc.x += bf2f(u.x); acc.y += bf2f(u.y);
        acc.z += bf2f(u.z); acc.w += bf2f(u.w);
    }
    ((float4*)out)[(size_t)r * 16 + f4] = acc;
}

// ---------------- R1 fallback kernels ----------------
__global__ __launch_bounds__(256) void gcn_gemm64(const float* __restrict__ X,
                                                  const float* __restrict__ W,
                                                  float* __restrict__ H,
                                                  int nrows) {
    __shared__ float Wl[64 * 64];
    __shared__ float Xl[16][65];
    const int tid = threadIdx.x;
    for (int i = tid; i < 1024; i += 256) ((float4*)Wl)[i] = ((const float4*)W)[i];
    const int rowBase = blockIdx.x * 16;
    const int lr = tid >> 4;
    const int lc = tid & 15;
    const int grow = rowBase + lr;
    if (grow < nrows) {
        float4 xv = ((const float4*)X)[(long long)grow * 16 + lc];
        Xl[lr][lc * 4 + 0] = xv.x; Xl[lr][lc * 4 + 1] = xv.y;
        Xl[lr][lc * 4 + 2] = xv.z; Xl[lr][lc * 4 + 3] = xv.w;
    }
    __syncthreads();
    float4 acc = make_float4(0.f, 0.f, 0.f, 0.f);
#pragma unroll
    for (int k = 0; k < 64; ++k) {
        const float xv = Xl[lr][k];
        const float4 w4 = ((float4*)Wl)[k * 16 + lc];
        acc.x = fmaf(xv, w4.x, acc.x); acc.y = fmaf(xv, w4.y, acc.y);
        acc.z = fmaf(xv, w4.z, acc.z); acc.w = fmaf(xv, w4.w, acc.w);
    }
    if (grow < nrows) ((float4*)H)[(long long)grow * 16 + lc] = acc;
}

__global__ __launch_bounds__(256) void gcn_scatter(const float* __restrict__ H,
                                                   const int* __restrict__ ei,
                                                   float* __restrict__ out,
                                                   int nedges) {
    const long long t = (long long)blockIdx.x * 256 + threadIdx.x;
    const int e = (int)(t >> 4);
    if (e >= nedges) return;
    const int lc = (int)(t & 15);
    const int s = ei[e];
    const int d = ei[nedges + e];
    const float4 v = ((const float4*)H)[(long long)s * 16 + lc];
    float* o = out + (long long)d * GCN_D + lc * 4;
    atomicAdd(o + 0, v.x);
    atomicAdd(o + 1, v.y);
    atomicAdd(o + 2, v.z);
    atomicAdd(o + 3, v.w);
}

extern "C" void kernel_launch(void* const* d_in, const int* in_sizes, int n_in,
                              void* d_out, int out_size, void* d_ws, size_t ws_size,
                              hipStream_t stream) {
    const float* x  = (const float*)d_in[0];
    const int*   ei = (const int*)d_in[1];   // [2,E] flat: src then dst (int32)
    const float* W0 = (const float*)d_in[2];
    const float* W1 = (const float*)d_in[3];
    const float* W2 = (const float*)d_in[4];
    float* out = (float*)d_out;

    const int N_ = in_sizes[0] / GCN_D;
    const int E_ = in_sizes[1] / 2;
    const int NSEG = (N_ + SEGROWS - 1) >> SEGSHIFT;

    // ws layout:
    //   B0 (N*64 bf16) | REG (max(N*64 bf16, E*4) -- B1/ebuf alias, disjoint
    //   lifetimes) | rp (N+2) | ghistP (512*CP) | csr0 (512*CP) | Wc | cs (E)
    uintptr_t base = (uintptr_t)d_ws;
    ushort* B0 = (ushort*)base;
    const size_t bfBytes  = (size_t)N_ * GCN_D * 2;
    const size_t regBytes = bfBytes > (size_t)E_ * 4 ? bfBytes : (size_t)E_ * 4;
    ushort*   B1   = (ushort*)(base + bfBytes);
    unsigned* ebuf = (unsigned*)B1;          // alias: dead before first agg
    int* rp     = (int*)(base + bfBytes + regBytes);
    int* ghistP = rp + (N_ + 2);
    int* csr0   = ghistP + MAXSEG * CP;
    float* Wc   = (float*)(csr0 + MAXSEG * CP);
    int* cs     = (int*)(Wc + 4096);
    const size_t needed = ((uintptr_t)(cs + E_) - base);

    const int gemmBlocks = (N_ + 63) / 64;
    const int gcBlocks = gemmBlocks > HISTB ? gemmBlocks : HISTB;

    if (NSEG <= MAXSEG && N_ < (1 << 24) && ws_size >= needed) {
        k_wchain<<<1, 256, 0, stream>>>(W0, W1, W2, Wc, ghistP, csr0);
        k_gemmcvt<<<gcBlocks, 256, 0, stream>>>(x, Wc, B0, ei, ghistP, N_, E_);
        k_apart<<<(E_ + A_EPB - 1) / A_EPB, 512, 0, stream>>>(ei, ghistP, csr0, ebuf, E_);
        k_bplace<<<NSEG, SEGROWS, 0, stream>>>(ebuf, ghistP, rp, cs, N_, E_);

        const int aggBlocks  = (N_ + 15) / 16;    // 4 rows/wave
        const int aggBlocks2 = (N_ + 31) / 32;    // 8 rows/wave
        k_aggc2<<<aggBlocks2, 256, 0, stream>>>(B0, rp, cs, B1, N_);  // a1 (16B/lane)
        k_aggc <<<aggBlocks,  256, 0, stream>>>(B1, rp, cs, B0, N_);  // a2 (8B/lane)
        k_aggw <<<aggBlocks,  256, 0, stream>>>(B0, rp, cs, out, N_); // a3 -> f32
    } else {
        // Fallback: R1 path (needs only h = N*64 f32).
        float* h = (float*)d_ws;
        const int scatBlocks = (int)(((long long)E_ * 16 + 255) / 256);
        const int gb16 = (N_ + 15) / 16;
        const float* curAct = x;
        for (int l = 0; l < 3; ++l) {
            const float* Wl = (l == 0) ? W0 : (l == 1) ? W1 : W2;
            gcn_gemm64<<<gb16, 256, 0, stream>>>(curAct, Wl, h, N_);
            hipMemsetAsync(out, 0, (size_t)N_ * GCN_D * sizeof(float), stream);
            gcn_scatter<<<scatBlocks, 256, 0, stream>>>(h, ei, out, E_);
            curAct = out;
        }
    }
}

// Round 15
// 154.550 us; speedup vs baseline: 1.0855x; 1.0299x over previous
//
#include <hip/hip_runtime.h>

// 3-layer GCN on MI355X:  out = S^3(x · (W0 W1 W2)),  S = scatter-add over E edges.
// N = 100000, E = 1200000, D = 64.
//
// Per launch (7 dispatches, no cross-call state):
//   k_wchain  : Wc = W0 @ W1 @ W2; zero ghistP + csr0  (1 block)
//   k_gemmcvt : B0 = bf16(x @ Wc), register-blocked 4x4, unroll-8;
//               first 512 blocks histogram dst segments (static 10-deep MLP
//               loads, padded 1-line-per-bin global accumulation)
//   k_apart   : local scan of ghistP + LDS counting-sort 4096-edge blocks ->
//               packed (src<<8|lr) per-segment runs (cursor = padded csr0)
//   k_bplace  : local scan + per-segment LDS counting sort -> rp + cs
//   k_aggc2 x2: agg layers 1-2 (8 lanes x 16 B, 8 rows/wave, bf16 out)
//   k_aggw2   : agg layer 3 (8 lanes x 16 B, f32 out)

#define GCN_D 64
#define SEGSHIFT 8
#define SEGROWS 256          // dst rows per segment
#define MAXSEG 512           // compile-time LDS capacity (N <= 131072)
#define A_EPB 4096           // edges per k_apart block
#define HISTB 512            // gemmcvt blocks that histogram
#define HITER 10             // static unroll depth: covers E <= 1,310,720
#define CP 16                // padding (ints) -> one 64B line per counter

typedef unsigned short ushort;

__device__ __forceinline__ float bf2f(ushort u) {
    union { unsigned u; float f; } c; c.u = ((unsigned)u) << 16; return c.f;
}
__device__ __forceinline__ float bflo(unsigned u) {
    union { unsigned u; float f; } c; c.u = u << 16; return c.f;
}
__device__ __forceinline__ float bfhi(unsigned u) {
    union { unsigned u; float f; } c; c.u = u & 0xFFFF0000u; return c.f;
}
// RNE f32 -> bf16 (finite inputs): add 0x7FFF + lsb(bit16), truncate.
__device__ __forceinline__ ushort f2bf(float f) {
    union { float f; unsigned u; } c; c.f = f;
    const unsigned r = 0x7FFFu + ((c.u >> 16) & 1u);
    return (ushort)((c.u + r) >> 16);
}
__device__ __forceinline__ unsigned pack2(float a, float b) {
    return (unsigned)f2bf(a) | ((unsigned)f2bf(b) << 16);
}

// ---------------- Wc = W0 @ W1 @ W2 (single block); zero ghistP/csr0 ---------
__global__ __launch_bounds__(256) void k_wchain(const float* __restrict__ W0,
                                                const float* __restrict__ W1,
                                                const float* __restrict__ W2,
                                                float* __restrict__ Wc,
                                                int* __restrict__ ghistP,
                                                int* __restrict__ csr0) {
    __shared__ float A[4096], B[4096], T[4096];
    const int t = threadIdx.x;
    for (int i = t; i < MAXSEG * CP; i += 256) { ghistP[i] = 0; csr0[i] = 0; }
    for (int i = t; i < 1024; i += 256) {
        ((float4*)A)[i] = ((const float4*)W0)[i];
        ((float4*)B)[i] = ((const float4*)W1)[i];
    }
    __syncthreads();
#pragma unroll
    for (int g = 0; g < 4; ++g) {
        const int idx = t + 256 * g;
        const int r = idx >> 4, c4 = idx & 15;
        float4 acc = make_float4(0.f, 0.f, 0.f, 0.f);
#pragma unroll
        for (int k = 0; k < 64; ++k) {
            const float a = A[r * 64 + k];
            const float4 b = ((float4*)B)[k * 16 + c4];
            acc.x = fmaf(a, b.x, acc.x); acc.y = fmaf(a, b.y, acc.y);
            acc.z = fmaf(a, b.z, acc.z); acc.w = fmaf(a, b.w, acc.w);
        }
        ((float4*)T)[idx] = acc;
    }
    __syncthreads();
    for (int i = t; i < 1024; i += 256) ((float4*)B)[i] = ((const float4*)W2)[i];
    __syncthreads();
#pragma unroll
    for (int g = 0; g < 4; ++g) {
        const int idx = t + 256 * g;
        const int r = idx >> 4, c4 = idx & 15;
        float4 acc = make_float4(0.f, 0.f, 0.f, 0.f);
#pragma unroll
        for (int k = 0; k < 64; ++k) {
            const float a = T[r * 64 + k];
            const float4 b = ((float4*)B)[k * 16 + c4];
            acc.x = fmaf(a, b.x, acc.x); acc.y = fmaf(a, b.y, acc.y);
            acc.z = fmaf(a, b.z, acc.z); acc.w = fmaf(a, b.w, acc.w);
        }
        ((float4*)Wc)[idx] = acc;
    }
}

// ---------------- GEMM + convert (+ fused hist: MLP loads, padded atomics) ---
__global__ __launch_bounds__(256, 3) void k_gemmcvt(const float* __restrict__ X,
                                                    const float* __restrict__ Wc,
                                                    ushort* __restrict__ B,
                                                    const int* __restrict__ ei,
                                                    int* __restrict__ ghistP,
                                                    int nrows, int E) {
    __shared__ float Wl[4096];
    __shared__ float Xl[64][68];
    __shared__ int h[MAXSEG];
    const int tid = threadIdx.x;
    for (int i = tid; i < 1024; i += 256) ((float4*)Wl)[i] = ((const float4*)Wc)[i];

    const int rowBase = blockIdx.x * 64;
    for (int i = tid; i < 1024; i += 256) {
        const int r = i >> 4, c4 = i & 15;
        const int gr = rowBase + r;
        const float4 v = (gr < nrows) ? ((const float4*)X)[(size_t)gr * 16 + c4]
                                      : make_float4(0.f, 0.f, 0.f, 0.f);
        *(float4*)&Xl[r][c4 * 4] = v;
    }
    __syncthreads();

    const int tr = tid >> 4;
    const int tc = tid & 15;
    float4 a0 = make_float4(0.f, 0.f, 0.f, 0.f);
    float4 a1 = a0, a2 = a0, a3 = a0;
#pragma unroll 8
    for (int k = 0; k < 64; ++k) {
        const float4 w4 = ((const float4*)Wl)[k * 16 + tc];
        const float x0 = Xl[tr][k];
        const float x1 = Xl[tr + 16][k];
        const float x2 = Xl[tr + 32][k];
        const float x3 = Xl[tr + 48][k];
        a0.x = fmaf(x0, w4.x, a0.x); a0.y = fmaf(x0, w4.y, a0.y);
        a0.z = fmaf(x0, w4.z, a0.z); a0.w = fmaf(x0, w4.w, a0.w);
        a1.x = fmaf(x1, w4.x, a1.x); a1.y = fmaf(x1, w4.y, a1.y);
        a1.z = fmaf(x1, w4.z, a1.z); a1.w = fmaf(x1, w4.w, a1.w);
        a2.x = fmaf(x2, w4.x, a2.x); a2.y = fmaf(x2, w4.y, a2.y);
        a2.z = fmaf(x2, w4.z, a2.z); a2.w = fmaf(x2, w4.w, a2.w);
        a3.x = fmaf(x3, w4.x, a3.x); a3.y = fmaf(x3, w4.y, a3.y);
        a3.z = fmaf(x3, w4.z, a3.z); a3.w = fmaf(x3, w4.w, a3.w);
    }
    {
        const int r0 = rowBase + tr;
        ushort4 o;
        if (r0 < nrows) {
            o.x = f2bf(a0.x); o.y = f2bf(a0.y); o.z = f2bf(a0.z); o.w = f2bf(a0.w);
            ((ushort4*)B)[(size_t)r0 * 16 + tc] = o;
        }
        if (r0 + 16 < nrows) {
            o.x = f2bf(a1.x); o.y = f2bf(a1.y); o.z = f2bf(a1.z); o.w = f2bf(a1.w);
            ((ushort4*)B)[(size_t)(r0 + 16) * 16 + tc] = o;
        }
        if (r0 + 32 < nrows) {
            o.x = f2bf(a2.x); o.y = f2bf(a2.y); o.z = f2bf(a2.z); o.w = f2bf(a2.w);
            ((ushort4*)B)[(size_t)(r0 + 32) * 16 + tc] = o;
        }
        if (r0 + 48 < nrows) {
            o.x = f2bf(a3.x); o.y = f2bf(a3.y); o.z = f2bf(a3.z); o.w = f2bf(a3.w);
            ((ushort4*)B)[(size_t)(r0 + 48) * 16 + tc] = o;
        }
    }

    // fused segment histogram: static unrolled loads (10 in flight) -> LDS
    // atomics -> padded global accumulate (one 64B line per bin).
    if (blockIdx.x < HISTB) {
        for (int i = tid; i < MAXSEG; i += 256) h[i] = 0;
        __syncthreads();
        const int stride = HISTB * 256;
        const int e0 = blockIdx.x * 256 + tid;
        int myd[HITER];
#pragma unroll
        for (int j = 0; j < HITER; ++j) {
            const int e = e0 + j * stride;
            myd[j] = (e < E) ? ei[E + e] : -1;
        }
#pragma unroll
        for (int j = 0; j < HITER; ++j)
            if (myd[j] >= 0) atomicAdd(&h[myd[j] >> SEGSHIFT], 1);
        for (int e = e0 + HITER * stride; e < E; e += stride)   // generality tail
            atomicAdd(&h[ei[E + e] >> SEGSHIFT], 1);
        __syncthreads();
        for (int i = tid; i < MAXSEG; i += 256) {
            const int c = h[i];
            if (c) atomicAdd(&ghistP[i * CP], c);
        }
    }
}

// ---------------- A-partition: local scan + LDS counting sort ----------------
// Packed word: (src << 8) | (dst & 255). src < 2^24 required.
__global__ __launch_bounds__(512) void k_apart(const int* __restrict__ ei,
                                               const int* __restrict__ ghistP,
                                               int* __restrict__ csr0,
                                               unsigned* __restrict__ ebuf, int E) {
    __shared__ int hist[MAXSEG], lofs[MAXSEG], cur[MAXSEG], gbase[MAXSEG], goffx[MAXSEG];
    __shared__ unsigned stg[A_EPB];
    __shared__ ushort stg2[A_EPB];
    const int t = threadIdx.x;
    const int base = blockIdx.x * A_EPB;
    const int cnt = min(A_EPB, E - base);

    // global exclusive offsets: scan padded ghist locally
    const int gv = ghistP[t * CP];
    goffx[t] = gv; __syncthreads();
    for (int off = 1; off < MAXSEG; off <<= 1) {
        const int y = (t >= off) ? goffx[t - off] : 0;
        __syncthreads();
        goffx[t] += y;
        __syncthreads();
    }
    const int gexcl = goffx[t] - gv;
    goffx[t] = gexcl;
    hist[t] = 0;
    __syncthreads();

    unsigned my[8]; int mb[8];
#pragma unroll
    for (int j = 0; j < 8; ++j) {
        const int i = t + j * 512;
        if (i < cnt) {
            const int e = base + i;
            const unsigned s = (unsigned)ei[e];
            const unsigned d = (unsigned)ei[E + e];
            my[j] = (s << 8) | (d & (SEGROWS - 1));
            mb[j] = (int)(d >> SEGSHIFT);
            atomicAdd(&hist[mb[j]], 1);
        } else mb[j] = -1;
    }
    __syncthreads();

    // exclusive block scan of hist -> lofs (and cursor copy)
    {
        const int v = hist[t];
        lofs[t] = v; __syncthreads();
        for (int off = 1; off < MAXSEG; off <<= 1) {
            const int y = (t >= off) ? lofs[t - off] : 0;
            __syncthreads();
            lofs[t] += y;
            __syncthreads();
        }
        const int excl = lofs[t] - v;
        __syncthreads();
        lofs[t] = excl; cur[t] = excl;
    }
    __syncthreads();

    // place packed words into stg grouped by segment; remember segment id
#pragma unroll
    for (int j = 0; j < 8; ++j) {
        if (mb[j] >= 0) {
            const int p = atomicAdd(&cur[mb[j]], 1);
            stg[p] = my[j];
            stg2[p] = (ushort)mb[j];
        }
    }
    __syncthreads();

    // reserve global space per segment (padded counters: 1 line each)
    {
        const int c = hist[t];
        const int p = c ? atomicAdd(&csr0[t * CP], c) : 0;
        gbase[t] = goffx[t] + p;
    }
    __syncthreads();

    // copy runs out (consecutive i within a run -> coalesced global writes)
    for (int i = t; i < cnt; i += 512) {
        const int b = (int)stg2[i];
        ebuf[(size_t)gbase[b] + (unsigned)(i - lofs[b])] = stg[i];
    }
}

// ---------------- B-place: local scan + per-segment counting sort ------------
__global__ __launch_bounds__(SEGROWS) void k_bplace(const unsigned* __restrict__ ebuf,
                                                    const int* __restrict__ ghistP,
                                                    int* __restrict__ rp,
                                                    int* __restrict__ cs, int N, int E) {
    __shared__ int h[SEGROWS], ofs[SEGROWS], gpart[SEGROWS];
    __shared__ int gx[MAXSEG], gcnt[MAXSEG];
    const int s = blockIdx.x;
    const int t = threadIdx.x;

    // scan padded ghist (2 segments per thread) -> gx
    const int a0 = ghistP[(2 * t) * CP];
    const int a1 = ghistP[(2 * t + 1) * CP];
    gcnt[2 * t] = a0; gcnt[2 * t + 1] = a1;
    const int ps = a0 + a1;
    gpart[t] = ps; __syncthreads();
    for (int off = 1; off < SEGROWS; off <<= 1) {
        const int y = (t >= off) ? gpart[t - off] : 0;
        __syncthreads();
        gpart[t] += y;
        __syncthreads();
    }
    const int ex = gpart[t] - ps;
    gx[2 * t] = ex;
    gx[2 * t + 1] = ex + a0;
    if (s == 0 && t == 0) rp[N] = E;
    __syncthreads();

    const int e0 = gx[s];
    const int e1 = e0 + gcnt[s];

    h[t] = 0; __syncthreads();
    for (int e = e0 + t; e < e1; e += SEGROWS)
        atomicAdd(&h[ebuf[e] & (SEGROWS - 1)], 1);
    __syncthreads();

    const int v = h[t];
    ofs[t] = v; __syncthreads();
    for (int off = 1; off < SEGROWS; off <<= 1) {
        const int y = (t >= off) ? ofs[t - off] : 0;
        __syncthreads();
        ofs[t] += y;
        __syncthreads();
    }
    const int excl = ofs[t] - v;
    const int r = s * SEGROWS + t;
    if (r < N) rp[r] = e0 + excl;
    __syncthreads();
    ofs[t] = excl;                 // becomes the within-segment cursor
    __syncthreads();

    for (int e = e0 + t; e < e1; e += SEGROWS) {
        const unsigned pr = ebuf[e];
        const int lr = (int)(pr & (SEGROWS - 1));
        const int p = atomicAdd(&ofs[lr], 1);
        cs[e0 + p] = (int)(pr >> 8);
    }
}

// ---------------- Agg (bf16 out): 8 lanes x 16 B, 8 rows/wave ----------------
__global__ __launch_bounds__(256) void k_aggc2(const ushort* __restrict__ B,
                                               const int* __restrict__ rp,
                                               const int* __restrict__ cs,
                                               ushort* __restrict__ out, int N) {
    const int t = threadIdx.x;
    const int gw = (blockIdx.x * 256 + t) >> 6;
    const int lane = t & 63;
    const int f8 = lane & 7;
    const int r = gw * 8 + (lane >> 3);
    if (r >= N) return;

    const int e0 = rp[r];
    const int e1 = rp[r + 1];
    const uint4* Bv = (const uint4*)B;

    float acc[8] = {0.f, 0.f, 0.f, 0.f, 0.f, 0.f, 0.f, 0.f};
    int e = e0;
    for (; e + 7 < e1; e += 8) {
        uint4 u[8];
#pragma unroll
        for (int j = 0; j < 8; ++j) u[j] = Bv[(size_t)cs[e + j] * 8 + f8];
#pragma unroll
        for (int j = 0; j < 8; ++j) {
            acc[0] += bflo(u[j].x); acc[1] += bfhi(u[j].x);
            acc[2] += bflo(u[j].y); acc[3] += bfhi(u[j].y);
            acc[4] += bflo(u[j].z); acc[5] += bfhi(u[j].z);
            acc[6] += bflo(u[j].w); acc[7] += bfhi(u[j].w);
        }
    }
    for (; e + 3 < e1; e += 4) {
        uint4 u[4];
#pragma unroll
        for (int j = 0; j < 4; ++j) u[j] = Bv[(size_t)cs[e + j] * 8 + f8];
#pragma unroll
        for (int j = 0; j < 4; ++j) {
            acc[0] += bflo(u[j].x); acc[1] += bfhi(u[j].x);
            acc[2] += bflo(u[j].y); acc[3] += bfhi(u[j].y);
            acc[4] += bflo(u[j].z); acc[5] += bfhi(u[j].z);
            acc[6] += bflo(u[j].w); acc[7] += bfhi(u[j].w);
        }
    }
    for (; e < e1; ++e) {
        const uint4 u = Bv[(size_t)cs[e] * 8 + f8];
        acc[0] += bflo(u.x); acc[1] += bfhi(u.x);
        acc[2] += bflo(u.y); acc[3] += bfhi(u.y);
        acc[4] += bflo(u.z); acc[5] += bfhi(u.z);
        acc[6] += bflo(u.w); acc[7] += bfhi(u.w);
    }
    uint4 o;
    o.x = pack2(acc[0], acc[1]); o.y = pack2(acc[2], acc[3]);
    o.z = pack2(acc[4], acc[5]); o.w = pack2(acc[6], acc[7]);
    ((uint4*)out)[(size_t)r * 8 + f8] = o;
}

// ---------------- Agg (f32 out): 8 lanes x 16 B, 8 rows/wave -----------------
__global__ __launch_bounds__(256) void k_aggw2(const ushort* __restrict__ B,
                                               const int* __restrict__ rp,
                                               const int* __restrict__ cs,
                                               float* __restrict__ out, int N) {
    const int t = threadIdx.x;
    const int gw = (blockIdx.x * 256 + t) >> 6;
    const int lane = t & 63;
    const int f8 = lane & 7;
    const int r = gw * 8 + (lane >> 3);
    if (r >= N) return;

    const int e0 = rp[r];
    const int e1 = rp[r + 1];
    const uint4* Bv = (const uint4*)B;

    float acc[8] = {0.f, 0.f, 0.f, 0.f, 0.f, 0.f, 0.f, 0.f};
    int e = e0;
    for (; e + 7 < e1; e += 8) {
        uint4 u[8];
#pragma unroll
        for (int j = 0; j < 8; ++j) u[j] = Bv[(size_t)cs[e + j] * 8 + f8];
#pragma unroll
        for (int j = 0; j < 8; ++j) {
            acc[0] += bflo(u[j].x); acc[1] += bfhi(u[j].x);
            acc[2] += bflo(u[j].y); acc[3] += bfhi(u[j].y);
            acc[4] += bflo(u[j].z); acc[5] += bfhi(u[j].z);
            acc[6] += bflo(u[j].w); acc[7] += bfhi(u[j].w);
        }
    }
    for (; e + 3 < e1; e += 4) {
        uint4 u[4];
#pragma unroll
        for (int j = 0; j < 4; ++j) u[j] = Bv[(size_t)cs[e + j] * 8 + f8];
#pragma unroll
        for (int j = 0; j < 4; ++j) {
            acc[0] += bflo(u[j].x); acc[1] += bfhi(u[j].x);
            acc[2] += bflo(u[j].y); acc[3] += bfhi(u[j].y);
            acc[4] += bflo(u[j].z); acc[5] += bfhi(u[j].z);
            acc[6] += bflo(u[j].w); acc[7] += bfhi(u[j].w);
        }
    }
    for (; e < e1; ++e) {
        const uint4 u = Bv[(size_t)cs[e] * 8 + f8];
        acc[0] += bflo(u.x); acc[1] += bfhi(u.x);
        acc[2] += bflo(u.y); acc[3] += bfhi(u.y);
        acc[4] += bflo(u.z); acc[5] += bfhi(u.z);
        acc[6] += bflo(u.w); acc[7] += bfhi(u.w);
    }
    float4 o0 = make_float4(acc[0], acc[1], acc[2], acc[3]);
    float4 o1 = make_float4(acc[4], acc[5], acc[6], acc[7]);
    ((float4*)out)[(size_t)r * 16 + f8 * 2 + 0] = o0;
    ((float4*)out)[(size_t)r * 16 + f8 * 2 + 1] = o1;
}

// ---------------- R1 fallback kernels ----------------
__global__ __launch_bounds__(256) void gcn_gemm64(const float* __restrict__ X,
                                                  const float* __restrict__ W,
                                                  float* __restrict__ H,
                                                  int nrows) {
    __shared__ float Wl[64 * 64];
    __shared__ float Xl[16][65];
    const int tid = threadIdx.x;
    for (int i = tid; i < 1024; i += 256) ((float4*)Wl)[i] = ((const float4*)W)[i];
    const int rowBase = blockIdx.x * 16;
    const int lr = tid >> 4;
    const int lc = tid & 15;
    const int grow = rowBase + lr;
    if (grow < nrows) {
        float4 xv = ((const float4*)X)[(long long)grow * 16 + lc];
        Xl[lr][lc * 4 + 0] = xv.x; Xl[lr][lc * 4 + 1] = xv.y;
        Xl[lr][lc * 4 + 2] = xv.z; Xl[lr][lc * 4 + 3] = xv.w;
    }
    __syncthreads();
    float4 acc = make_float4(0.f, 0.f, 0.f, 0.f);
#pragma unroll
    for (int k = 0; k < 64; ++k) {
        const float xv = Xl[lr][k];
        const float4 w4 = ((float4*)Wl)[k * 16 + lc];
        acc.x = fmaf(xv, w4.x, acc.x); acc.y = fmaf(xv, w4.y, acc.y);
        acc.z = fmaf(xv, w4.z, acc.z); acc.w = fmaf(xv, w4.w, acc.w);
    }
    if (grow < nrows) ((float4*)H)[(long long)grow * 16 + lc] = acc;
}

__global__ __launch_bounds__(256) void gcn_scatter(const float* __restrict__ H,
                                                   const int* __restrict__ ei,
                                                   float* __restrict__ out,
                                                   int nedges) {
    const long long t = (long long)blockIdx.x * 256 + threadIdx.x;
    const int e = (int)(t >> 4);
    if (e >= nedges) return;
    const int lc = (int)(t & 15);
    const int s = ei[e];
    const int d = ei[nedges + e];
    const float4 v = ((const float4*)H)[(long long)s * 16 + lc];
    float* o = out + (long long)d * GCN_D + lc * 4;
    atomicAdd(o + 0, v.x);
    atomicAdd(o + 1, v.y);
    atomicAdd(o + 2, v.z);
    atomicAdd(o + 3, v.w);
}

extern "C" void kernel_launch(void* const* d_in, const int* in_sizes, int n_in,
                              void* d_out, int out_size, void* d_ws, size_t ws_size,
                              hipStream_t stream) {
    const float* x  = (const float*)d_in[0];
    const int*   ei = (const int*)d_in[1];   // [2,E] flat: src then dst (int32)
    const float* W0 = (const float*)d_in[2];
    const float* W1 = (const float*)d_in[3];
    const float* W2 = (const float*)d_in[4];
    float* out = (float*)d_out;

    const int N_ = in_sizes[0] / GCN_D;
    const int E_ = in_sizes[1] / 2;
    const int NSEG = (N_ + SEGROWS - 1) >> SEGSHIFT;

    // ws layout:
    //   B0 (N*64 bf16) | REG (max(N*64 bf16, E*4) -- B1/ebuf alias, disjoint
    //   lifetimes) | rp (N+2) | ghistP (512*CP) | csr0 (512*CP) | Wc | cs (E)
    uintptr_t base = (uintptr_t)d_ws;
    ushort* B0 = (ushort*)base;
    const size_t bfBytes  = (size_t)N_ * GCN_D * 2;
    const size_t regBytes = bfBytes > (size_t)E_ * 4 ? bfBytes : (size_t)E_ * 4;
    ushort*   B1   = (ushort*)(base + bfBytes);
    unsigned* ebuf = (unsigned*)B1;          // alias: dead before first agg
    int* rp     = (int*)(base + bfBytes + regBytes);
    int* ghistP = rp + (N_ + 2);
    int* csr0   = ghistP + MAXSEG * CP;
    float* Wc   = (float*)(csr0 + MAXSEG * CP);
    int* cs     = (int*)(Wc + 4096);
    const size_t needed = ((uintptr_t)(cs + E_) - base);

    const int gemmBlocks = (N_ + 63) / 64;
    const int gcBlocks = gemmBlocks > HISTB ? gemmBlocks : HISTB;

    if (NSEG <= MAXSEG && N_ < (1 << 24) && ws_size >= needed) {
        k_wchain<<<1, 256, 0, stream>>>(W0, W1, W2, Wc, ghistP, csr0);
        k_gemmcvt<<<gcBlocks, 256, 0, stream>>>(x, Wc, B0, ei, ghistP, N_, E_);
        k_apart<<<(E_ + A_EPB - 1) / A_EPB, 512, 0, stream>>>(ei, ghistP, csr0, ebuf, E_);
        k_bplace<<<NSEG, SEGROWS, 0, stream>>>(ebuf, ghistP, rp, cs, N_, E_);

        const int aggBlocks2 = (N_ + 31) / 32;    // 8 rows/wave, 4 waves/block
        k_aggc2<<<aggBlocks2, 256, 0, stream>>>(B0, rp, cs, B1, N_);  // a1
        k_aggc2<<<aggBlocks2, 256, 0, stream>>>(B1, rp, cs, B0, N_);  // a2
        k_aggw2<<<aggBlocks2, 256, 0, stream>>>(B0, rp, cs, out, N_); // a3 -> f32
    } else {
        // Fallback: R1 path (needs only h = N*64 f32).
        float* h = (float*)d_ws;
        const int scatBlocks = (int)(((long long)E_ * 16 + 255) / 256);
        const int gb16 = (N_ + 15) / 16;
        const float* curAct = x;
        for (int l = 0; l < 3; ++l) {
            const float* Wl = (l == 0) ? W0 : (l == 1) ? W1 : W2;
            gcn_gemm64<<<gb16, 256, 0, stream>>>(curAct, Wl, h, N_);
            hipMemsetAsync(out, 0, (size_t)N_ * GCN_D * sizeof(float), stream);
            gcn_scatter<<<scatBlocks, 256, 0, stream>>>(h, ei, out, E_);
            curAct = out;
        }
    }
}